// Round 10
// baseline (282.061 us; speedup 1.0000x reference)
//
#include <hip/hip_runtime.h>
#include <stdint.h>

// K-Planes hash-grid encoder, MI355X.  Round 10.
// Request ledger (r1-r9): ~4.6us per MILLION divergent vector-memory lane-
// requests, locality-independent. Structure (Plan A):
//  memset: zero hist[768]+cursor[768] (graph-capturable)
//  K0 packhist: pts -> pts2[plane][pt] + LDS->global 16x16 bucket histogram
//  K1 scatter: per-block LDS scan of hist row -> counting-sort points into
//     sort16[plane] (atomic order irrelevant to output values)
//  K2 lowhi FUSED: blocks [0,768) = low: per (plane,bucket) stage 12 level-
//     rects (<=3961 float2, 31.3KB LDS incl. carved scan/meta -> 5 blk/CU),
//     interp l0-11, scatter 96B rows ws2[orig][plane][12].
//     blocks [768,6912) = hi: levels 12-15 direct gather, XCD-pinned b&7
//     (768%8==0 preserves mapping), float4 even-u0 corner pairing, 4 pts/thr.
//     Low is LDS/VALU-pipe, hi is TA-pipe -> dispatched-first low overlaps.
//  K3 comb: ws2 + wsH -> out, fully coalesced via LDS tile.
// Fallbacks: Plan B (r2 3-pass + transpose), mono.

#define NPTS   524288u
#define TSIZE  524288u
#define TMASK  0x7FFFFu
#define PRIME1 2654435761u

__constant__ float c_res[16] = {
    16.f, 22.f, 30.f, 42.f, 58.f, 80.f, 111.f, 153.f,
    212.f, 294.f, 406.f, 561.f, 775.f, 1072.f, 1481.f, 2047.f
};
__constant__ int c_resiLow[12] = {16, 22, 30, 42, 58, 80, 111, 153, 212, 294, 406, 561};

// ---------------- K0: pack per-plane coords + bucket histogram --------------
__global__ __launch_bounds__(256) void k_packhist(
    const float* __restrict__ pts, float2* __restrict__ pts2,
    uint32_t* __restrict__ hist)
{
    __shared__ uint32_t lh[768];
    const uint32_t b = blockIdx.x, t = threadIdx.x;
    lh[t] = 0u; lh[t + 256u] = 0u; lh[t + 512u] = 0u;
    __syncthreads();
    const uint32_t pt = b * 256u + t;
    const float x = pts[pt * 3u + 0u];
    const float y = pts[pt * 3u + 1u];
    const float z = pts[pt * 3u + 2u];
    pts2[            pt] = make_float2(x, y);
    pts2[NPTS      + pt] = make_float2(x, z);
    pts2[2u * NPTS + pt] = make_float2(y, z);
    const uint32_t bx = min(15u, (uint32_t)(x * 16.f));
    const uint32_t by = min(15u, (uint32_t)(y * 16.f));
    const uint32_t bz = min(15u, (uint32_t)(z * 16.f));
    atomicAdd(&lh[         bx * 16u + by], 1u);
    atomicAdd(&lh[256u +   bx * 16u + bz], 1u);
    atomicAdd(&lh[512u +   by * 16u + bz], 1u);
    __syncthreads();
    if (lh[t])        atomicAdd(&hist[t],        lh[t]);
    if (lh[t + 256u]) atomicAdd(&hist[t + 256u], lh[t + 256u]);
    if (lh[t + 512u]) atomicAdd(&hist[t + 512u], lh[t + 512u]);
}

// ---------------- K1: scatter into bucket order (local scan) ----------------
__global__ __launch_bounds__(256) void k_scatter(
    const float2* __restrict__ pts2, const uint32_t* __restrict__ hist,
    uint32_t* __restrict__ cursor, float4* __restrict__ sort16)
{
    __shared__ uint32_t su[256], lcnt[256], gb[256], lc2[256];
    const uint32_t b = blockIdx.x, t = threadIdx.x;
    const uint32_t plane = b >> 6, chunk = b & 63u;
    const uint32_t h = hist[plane * 256u + t];
    su[t] = h; lcnt[t] = 0u; lc2[t] = 0u;
    __syncthreads();
    for (uint32_t off = 1u; off < 256u; off <<= 1) {   // inclusive scan
        uint32_t v = 0u;
        if (t >= off) v = su[t - off];
        __syncthreads();
        su[t] += v;
        __syncthreads();
    }
    const uint32_t mybase = su[t] - h;                 // exclusive base
    const float2* __restrict__ pp = pts2 + (size_t)plane * NPTS;
    const uint32_t pt0 = chunk * 8192u + t;
    for (uint32_t k = 0; k < 32u; ++k) {
        const float2 c = pp[pt0 + k * 256u];
        const uint32_t bb = min(15u, (uint32_t)(c.x * 16.f)) * 16u
                          + min(15u, (uint32_t)(c.y * 16.f));
        atomicAdd(&lcnt[bb], 1u);
    }
    __syncthreads();
    gb[t] = mybase + atomicAdd(&cursor[plane * 256u + t], lcnt[t]);
    __syncthreads();
    float4* __restrict__ sp = sort16 + (size_t)plane * NPTS;
    for (uint32_t k = 0; k < 32u; ++k) {
        const uint32_t pt = pt0 + k * 256u;
        const float2 c = pp[pt];
        const uint32_t bb = min(15u, (uint32_t)(c.x * 16.f)) * 16u
                          + min(15u, (uint32_t)(c.y * 16.f));
        const uint32_t r = atomicAdd(&lc2[bb], 1u);
        sp[gb[bb] + r] = make_float4(c.x, c.y, __uint_as_float(pt), 0.f);
    }
}

// ---------------- K2: FUSED low (l0-11 bucket-LDS) + hi (l12-15 gather) -----
__global__ __launch_bounds__(256) void k_lowhi(
    const float2* __restrict__ pts2, const float4* __restrict__ sort16,
    const uint32_t* __restrict__ hist, const float2* __restrict__ tab,
    float2* __restrict__ ws2, float2* __restrict__ wsH)
{
    __shared__ float2 sm[4000];              // 32000 B total -> 5 blocks/CU
    const uint32_t b = blockIdx.x, t = threadIdx.x;

    if (b < 768u) {
        // ======== low region: one (plane,bucket), levels 0-11 ========
        const uint32_t plane  = b >> 8;
        const uint32_t bucket = b & 255u;
        const uint32_t bx = bucket >> 4, by = bucket & 15u;

        // local exclusive scan of hist row (scan ws carved from sm)
        uint32_t* su = (uint32_t*)sm;
        const uint32_t h = hist[plane * 256u + t];
        su[t] = h;
        __syncthreads();
        for (uint32_t off = 1u; off < 256u; off <<= 1) {
            uint32_t v = 0u;
            if (t >= off) v = su[t - off];
            __syncthreads();
            su[t] += v;
            __syncthreads();
        }
        const uint32_t cntB  = hist[plane * 256u + bucket];  // broadcast
        const uint32_t start = su[bucket] - cntB;
        __syncthreads();

        // rect metadata carved at sm[3968..4000) (64 uints; rects <= 3961)
        uint32_t* Pm = (uint32_t*)(sm + 3968);
        if (t == 0u) {
            uint32_t off = 0u;
            for (uint32_t l = 0; l < 12u; ++l) {
                const int R = c_resiLow[l];
                const int u0s = max(0, (int)((bx * (uint32_t)R) >> 4) - 1);
                const int u0e = min(R, (int)(((bx + 1u) * (uint32_t)R) >> 4) + 2);
                const int u1s = max(0, (int)((by * (uint32_t)R) >> 4) - 1);
                const int u1e = min(R, (int)(((by + 1u) * (uint32_t)R) >> 4) + 2);
                const uint32_t rows = (uint32_t)(u0e - u0s + 1);
                const uint32_t cols = (uint32_t)(u1e - u1s + 1);
                Pm[l] = off; Pm[12u + l] = (uint32_t)u0s;
                Pm[24u + l] = (uint32_t)u1s; Pm[36u + l] = cols;
                Pm[48u + l] = rows;
                off += rows * cols;
            }
        }
        __syncthreads();

        for (uint32_t l = 0; l < 12u; ++l) { // divergent hash staging (once)
            const uint32_t off  = Pm[l];
            const uint32_t u0s  = Pm[12u + l], u1s = Pm[24u + l];
            const uint32_t cols = Pm[36u + l], rows = Pm[48u + l];
            const uint32_t E    = rows * cols;
            const uint32_t tb   = (plane * 16u + l) * TSIZE;
            for (uint32_t i = t; i < E; i += 256u) {
                const uint32_t r  = i / cols;
                const uint32_t cx = u0s + r;
                const uint32_t cy = u1s + (i - r * cols);
                sm[off + i] = tab[tb + ((cx ^ (cy * PRIME1)) & TMASK)];
            }
        }
        __syncthreads();

        const float4* __restrict__ sp = sort16 + (size_t)plane * NPTS;
        float4* __restrict__ w4 = (float4*)ws2;
        for (uint32_t i = t; i < cntB; i += 256u) {
            const float4 f = sp[start + i];
            const float c0 = f.x, c1 = f.y;
            const uint32_t orig = __float_as_uint(f.z);
            float2 acc[12];
#pragma unroll
            for (int l = 0; l < 12; ++l) {
                const float res = c_res[l];
                const float s0 = c0 * res;
                const float s1 = c1 * res;
                const float f0 = floorf(s0);
                const float f1 = floorf(s1);
                const float r0 = s0 - f0;    // exact f32 match to reference
                const float r1 = s1 - f1;
                const uint32_t u0 = (uint32_t)f0, u1 = (uint32_t)f1;
                const uint32_t cols = Pm[36u + l];
                const uint32_t ci = Pm[l] + (u0 - Pm[12u + l]) * cols
                                  + (u1 - Pm[24u + l]);
                const float2 q00 = sm[ci];
                const float2 q01 = sm[ci + 1u];
                const float2 q10 = sm[ci + cols];
                const float2 q11 = sm[ci + cols + 1u];
                const float w00 = (1.f - r0) * (1.f - r1);
                const float w01 = (1.f - r0) * r1;
                const float w10 = r0 * (1.f - r1);
                const float w11 = r0 * r1;
                acc[l] = make_float2(
                    w00 * q00.x + w01 * q01.x + w10 * q10.x + w11 * q11.x,
                    w00 * q00.y + w01 * q01.y + w10 * q10.y + w11 * q11.y);
            }
            const size_t d = (size_t)orig * 18u + (size_t)plane * 6u;
            w4[d + 0] = make_float4(acc[0].x, acc[0].y, acc[1].x, acc[1].y);
            w4[d + 1] = make_float4(acc[2].x, acc[2].y, acc[3].x, acc[3].y);
            w4[d + 2] = make_float4(acc[4].x, acc[4].y, acc[5].x, acc[5].y);
            w4[d + 3] = make_float4(acc[6].x, acc[6].y, acc[7].x, acc[7].y);
            w4[d + 4] = make_float4(acc[8].x, acc[8].y, acc[9].x, acc[9].y);
            w4[d + 5] = make_float4(acc[10].x, acc[10].y, acc[11].x, acc[11].y);
        }
        return;
    }

    // ======== hi region: levels 12-15 direct gather (r9-proven) ========
    const uint32_t hb  = b - 768u;           // 768%8==0: b&7 mapping kept
    const uint32_t xcd = hb & 7u;
    const uint32_t s   = hb >> 3;            // 0..767
    uint32_t g, chunk;
    if (s < 512u) { g = xcd; chunk = s; }                    // groups 0-7 full
    else { g = 8u + (xcd >> 1); chunk = ((xcd & 1u) << 8) + (s - 512u); }
    const uint32_t plane = g % 3u;
    const uint32_t lvl   = 12u + g / 3u;
    const uint32_t gabs  = plane * 16u + lvl;
    const float    res   = c_res[lvl];
    const uint32_t tb    = gabs * TSIZE;
    const float4* __restrict__ tab4 = (const float4*)tab;
    const uint32_t b4    = gabs * (TSIZE / 2u);
    const float2* __restrict__ pp = pts2 + (size_t)plane * NPTS;
    const uint32_t pt0   = chunk * 1024u + t;

    float4 P0[4], P1[4];
    float2 Q0[4], Q1[4];
    float  r0[4], r1[4];
    uint32_t sel0[4], sel1[4], oddm[4];

#pragma unroll
    for (int k = 0; k < 4; ++k) {            // issue all loads first
        const uint32_t pt = pt0 + (uint32_t)k * 256u;
        const float2 c2 = pp[pt];
        const float s0 = c2.x * res;
        const float s1 = c2.y * res;
        const float f0 = floorf(s0);
        const float f1 = floorf(s1);
        r0[k] = s0 - f0;                     // exact f32 match to reference
        r1[k] = s1 - f1;
        const uint32_t u0  = (uint32_t)f0;
        const uint32_t hy0 = (uint32_t)f1 * PRIME1;
        const uint32_t hy1 = hy0 + PRIME1;
        const uint32_t i00 = ( u0        ^ hy0) & TMASK;
        const uint32_t i01 = ( u0        ^ hy1) & TMASK;
        const uint32_t i10 = ((u0 + 1u)  ^ hy0) & TMASK;
        const uint32_t i11 = ((u0 + 1u)  ^ hy1) & TMASK;
        sel0[k] = i00 & 1u;
        sel1[k] = i01 & 1u;
        oddm[k] = u0 & 1u;
        P0[k] = tab4[b4 + (i00 >> 1)];       // covers t00 (+t10 if u0 even)
        P1[k] = tab4[b4 + (i01 >> 1)];       // covers t01 (+t11 if u0 even)
        Q0[k] = make_float2(0.f, 0.f);
        Q1[k] = make_float2(0.f, 0.f);
        if (oddm[k]) {                       // exec-masked, ~50% lanes
            Q0[k] = tab[tb + i10];
            Q1[k] = tab[tb + i11];
        }
    }
#pragma unroll
    for (int k = 0; k < 4; ++k) {
        const uint32_t pt = pt0 + (uint32_t)k * 256u;
        const float2 lo0 = make_float2(P0[k].x, P0[k].y);
        const float2 hi0 = make_float2(P0[k].z, P0[k].w);
        const float2 lo1 = make_float2(P1[k].x, P1[k].y);
        const float2 hi1 = make_float2(P1[k].z, P1[k].w);
        const float2 t00 = sel0[k] ? hi0 : lo0;
        const float2 t01 = sel1[k] ? hi1 : lo1;
        const float2 t10 = oddm[k] ? Q0[k] : (sel0[k] ? lo0 : hi0);
        const float2 t11 = oddm[k] ? Q1[k] : (sel1[k] ? lo1 : hi1);
        const float w00 = (1.f - r0[k]) * (1.f - r1[k]);
        const float w01 = (1.f - r0[k]) * r1[k];
        const float w10 = r0[k] * (1.f - r1[k]);
        const float w11 = r0[k] * r1[k];
        wsH[(size_t)g * NPTS + pt] = make_float2(
            w00 * t00.x + w01 * t01.x + w10 * t10.x + w11 * t11.x,
            w00 * t00.y + w01 * t01.y + w10 * t10.y + w11 * t11.y);
    }
}

// ---------------- K3: combine -> out (fully coalesced) ----------------------
__global__ __launch_bounds__(256) void k_comb(
    const float2* __restrict__ ws2, const float2* __restrict__ wsH,
    float2* __restrict__ out)
{
    __shared__ float2 s2[2304];              // 64 pts x 36
    __shared__ float2 sh[768];               // 12 groups x 64 pts
    const uint32_t b = blockIdx.x, t = threadIdx.x;
    const uint32_t pt0 = b * 64u;
    const float2* __restrict__ src = ws2 + (size_t)pt0 * 36u;
    for (uint32_t i = t; i < 2304u; i += 256u) s2[i] = src[i];
    for (uint32_t i = t; i < 768u; i += 256u) {
        const uint32_t j = i >> 6, p = i & 63u;
        sh[i] = wsH[(size_t)j * NPTS + pt0 + p];
    }
    __syncthreads();
#pragma unroll
    for (uint32_t k = 0; k < 4u; ++k) {
        const uint32_t e = t + k * 256u;
        const uint32_t pt = e >> 4, l = e & 15u;
        float2 v;
        if (l < 12u) {
            const float2 a  = s2[pt * 36u + l];
            const float2 bb = s2[pt * 36u + 12u + l];
            const float2 c  = s2[pt * 36u + 24u + l];
            v = make_float2(a.x * bb.x * c.x, a.y * bb.y * c.y);
        } else {
            const uint32_t j0 = (l - 12u) * 3u;
            const float2 a  = sh[j0 * 64u + pt];
            const float2 bb = sh[(j0 + 1u) * 64u + pt];
            const float2 c  = sh[(j0 + 2u) * 64u + pt];
            v = make_float2(a.x * bb.x * c.x, a.y * bb.y * c.y);
        }
        out[(size_t)(pt0 + pt) * 16u + l] = v;
    }
}

// ---------------- Plan B fallback: r2 3-pass + transpose --------------------
template <int P, bool FIRST>
__global__ __launch_bounds__(256) void kplane_pass(
    const float* __restrict__ pts, const float2* __restrict__ tab,
    float2* __restrict__ ws)
{
    const uint32_t b     = blockIdx.x;
    const uint32_t xcd   = b & 7u;
    const uint32_t s     = b >> 3;
    const uint32_t gi    = s >> 11;
    const uint32_t chunk = s & 2047u;
    const uint32_t lvl   = gi * 8u + xcd;
    const uint32_t pt    = chunk * 256u + threadIdx.x;
    constexpr int c0 = (P == 2) ? 1 : 0;
    constexpr int c1 = (P == 0) ? 1 : 2;
    const float a0  = pts[pt * 3u + c0];
    const float a1  = pts[pt * 3u + c1];
    const float res = c_res[lvl];
    const float s0 = a0 * res;
    const float s1 = a1 * res;
    const float f0 = floorf(s0);
    const float f1 = floorf(s1);
    const float r0 = s0 - f0;
    const float r1 = s1 - f1;
    const uint32_t u0 = (uint32_t)f0;
    const uint32_t hy0  = (uint32_t)f1 * PRIME1;
    const uint32_t hy1  = hy0 + PRIME1;
    const uint32_t base = ((uint32_t)P * 16u + lvl) * TSIZE;
    const float2 t00 = tab[base + (( u0       ^ hy0) & TMASK)];
    const float2 t01 = tab[base + (( u0       ^ hy1) & TMASK)];
    const float2 t10 = tab[base + (((u0 + 1u) ^ hy0) & TMASK)];
    const float2 t11 = tab[base + (((u0 + 1u) ^ hy1) & TMASK)];
    const float w00 = (1.f - r0) * (1.f - r1);
    const float w01 = (1.f - r0) * r1;
    const float w10 = r0 * (1.f - r1);
    const float w11 = r0 * r1;
    const float e0 = w00 * t00.x + w01 * t01.x + w10 * t10.x + w11 * t11.x;
    const float e1 = w00 * t00.y + w01 * t01.y + w10 * t10.y + w11 * t11.y;
    const uint32_t widx = lvl * NPTS + pt;
    if (FIRST) {
        ws[widx] = make_float2(e0, e1);
    } else {
        const float2 prev = ws[widx];
        ws[widx] = make_float2(prev.x * e0, prev.y * e1);
    }
}

__global__ __launch_bounds__(256) void kplane_transpose(
    const float2* __restrict__ ws, float2* __restrict__ out)
{
    const uint32_t tid = blockIdx.x * 256u + threadIdx.x;
    const uint32_t lvl = tid & 15u;
    const uint32_t pt  = tid >> 4;
    out[tid] = ws[lvl * NPTS + pt];
}

__global__ __launch_bounds__(256) void kplane_mono(
    const float* __restrict__ pts, const float2* __restrict__ tab,
    float2* __restrict__ out)
{
    const uint32_t tid = blockIdx.x * 256u + threadIdx.x;
    const uint32_t pt  = tid >> 4;
    const uint32_t lvl = tid & 15u;
    const float x = pts[pt * 3u + 0u];
    const float y = pts[pt * 3u + 1u];
    const float z = pts[pt * 3u + 2u];
    const float res = c_res[lvl];
    const float a0[3] = {x, x, y};
    const float a1[3] = {y, z, z};
    float p0 = 1.f, p1 = 1.f;
#pragma unroll
    for (int pl = 0; pl < 3; ++pl) {
        const float s0 = a0[pl] * res;
        const float s1 = a1[pl] * res;
        const float f0 = floorf(s0);
        const float f1 = floorf(s1);
        const float r0 = s0 - f0;
        const float r1 = s1 - f1;
        const uint32_t u0 = (uint32_t)f0;
        const uint32_t hy0 = (uint32_t)f1 * PRIME1;
        const uint32_t hy1 = hy0 + PRIME1;
        const uint32_t base = ((uint32_t)pl * 16u + lvl) * TSIZE;
        const float2 t00 = tab[base + (( u0       ^ hy0) & TMASK)];
        const float2 t01 = tab[base + (( u0       ^ hy1) & TMASK)];
        const float2 t10 = tab[base + (((u0 + 1u) ^ hy0) & TMASK)];
        const float2 t11 = tab[base + (((u0 + 1u) ^ hy1) & TMASK)];
        const float w00 = (1.f - r0) * (1.f - r1);
        const float w01 = (1.f - r0) * r1;
        const float w10 = r0 * (1.f - r1);
        const float w11 = r0 * r1;
        p0 *= w00 * t00.x + w01 * t01.x + w10 * t10.x + w11 * t11.x;
        p1 *= w00 * t00.y + w01 * t01.y + w10 * t10.y + w11 * t11.y;
    }
    out[pt * 16u + lvl] = make_float2(p0, p1);
}

extern "C" void kernel_launch(void* const* d_in, const int* in_sizes, int n_in,
                              void* d_out, int out_size, void* d_ws, size_t ws_size,
                              hipStream_t stream) {
    const float*  pts = (const float*)d_in[0];
    const float2* tab = (const float2*)d_in[1];
    float2*       out = (float2*)d_out;

    const size_t wsA = (size_t)48 * NPTS * sizeof(float2);   // 201.3 MB
    const size_t wsB = (size_t)16 * NPTS * sizeof(float2);   //  67.1 MB
    dim3 block256(256u);

    if (ws_size >= wsA) {
        // d_out scratch: pts2 (12.6MB) | sort16 (25.2MB) | hist | cursor
        float2*   pts2   = (float2*)d_out;
        float4*   sort16 = (float4*)(pts2 + (size_t)3 * NPTS);
        uint32_t* hist   = (uint32_t*)(sort16 + (size_t)3 * NPTS);
        uint32_t* cursor = hist + 768;
        // d_ws: ws2 [pt][plane][12] (151MB) | wsH [12][NPTS] (50.3MB)
        float2* ws2 = (float2*)d_ws;
        float2* wsH = ws2 + (size_t)36 * NPTS;

        hipMemsetAsync(hist, 0, 1536u * sizeof(uint32_t), stream);
        hipLaunchKernelGGL(k_packhist, dim3(2048u), block256, 0, stream,
                           pts, pts2, hist);
        hipLaunchKernelGGL(k_scatter,  dim3(192u),  block256, 0, stream,
                           pts2, hist, cursor, sort16);
        hipLaunchKernelGGL(k_lowhi,    dim3(6912u), block256, 0, stream,
                           pts2, sort16, hist, tab, ws2, wsH);
        hipLaunchKernelGGL(k_comb,     dim3(NPTS / 64u), block256, 0, stream,
                           ws2, wsH, out);
    } else if (ws_size >= wsB) {
        float2* ws = (float2*)d_ws;
        dim3 grid(16u * (NPTS / 256u));
        hipLaunchKernelGGL((kplane_pass<0, true >), grid, block256, 0, stream, pts, tab, ws);
        hipLaunchKernelGGL((kplane_pass<1, false>), grid, block256, 0, stream, pts, tab, ws);
        hipLaunchKernelGGL((kplane_pass<2, false>), grid, block256, 0, stream, pts, tab, ws);
        dim3 tgrid((NPTS * 16u) / 256u);
        hipLaunchKernelGGL(kplane_transpose, tgrid, block256, 0, stream, ws, out);
    } else {
        dim3 grid((NPTS * 16u) / 256u);
        hipLaunchKernelGGL(kplane_mono, grid, block256, 0, stream, pts, tab, out);
    }
}